// Round 4
// baseline (1468.674 us; speedup 1.0000x reference)
//
#include <hip/hip_runtime.h>

typedef unsigned int u32;
typedef unsigned long long u64;
typedef unsigned short u16;

#define M_ROWS 32768
#define DB 256
#define DIN 1024
#define KCODES 16384

typedef __attribute__((ext_vector_type(8))) short bf16x8;   // 8 bf16 = 4 VGPR (MFMA A/B frag)
typedef __attribute__((ext_vector_type(4))) float f32x4;    // MFMA C/D frag
typedef __attribute__((ext_vector_type(8))) unsigned short us8;

// async global->LDS, 16B per lane; LDS dst = wave-uniform base + lane*16
#define GLOAD16(gp, lp) __builtin_amdgcn_global_load_lds( \
    (const __attribute__((address_space(1))) unsigned int*)(gp), \
    (__attribute__((address_space(3))) unsigned int*)(lp), 16, 0, 0)

// order-preserving fp32 -> u32 (finite values)
__device__ __forceinline__ u32 ford(float f) {
    u32 u = __float_as_uint(f);
    return (u & 0x80000000u) ? ~u : (u | 0x80000000u);
}
__device__ __forceinline__ u64 shfl_xor_u64(u64 v, int m) {
    u32 lo = (u32)v, hi = (u32)(v >> 32);
    lo = (u32)__shfl_xor((int)lo, m, 64);
    hi = (u32)__shfl_xor((int)hi, m, 64);
    return ((u64)hi << 32) | lo;
}
__device__ __forceinline__ u16 f2bf_rne(float f) {
    const u32 u = __float_as_uint(f);
    return (u16)((u + 0x7FFFu + ((u >> 16) & 1u)) >> 16);
}

// ---------------------------------------------------------------------------
// C(f32)[M,N] = A(f32)[M,Kd] @ B(f32)[Kd,N] + bias(f32)[N]
// block tile 128x128, BK=16, thread tile 8x8, 256 threads. (unchanged, verified)
__global__ __launch_bounds__(256)
void sgemm_f32(const float* __restrict__ A, int lda,
               const float* __restrict__ B, int ldb,
               const float* __restrict__ bias,
               float* __restrict__ C, int ldc, int Kd)
{
    __shared__ float As[16][132];
    __shared__ float Bs[16][132];
    const int t = threadIdx.x;
    const int w = t >> 6, lane = t & 63;
    const int tx = (lane & 7) | ((w & 1) << 3);
    const int ty = ((lane >> 3) & 7) | ((w >> 1) << 3);
    const int rb = blockIdx.x << 7;
    const int cb = blockIdx.y << 7;

    const int sr  = t >> 1;
    const int sk8 = (t & 1) << 3;
    const int bkr = t >> 4;
    const int bc8 = (t & 15) << 3;

    const float* Ap = A + (size_t)(rb + sr) * lda + sk8;
    const float* Bp = B + (size_t)bkr * ldb + cb + bc8;

    float acc[8][8];
#pragma unroll
    for (int i = 0; i < 8; ++i)
#pragma unroll
        for (int j = 0; j < 8; ++j) acc[i][j] = 0.0f;

    float4 a0 = *(const float4*)Ap;
    float4 a1 = *(const float4*)(Ap + 4);
    float4 b0 = *(const float4*)Bp;
    float4 b1 = *(const float4*)(Bp + 4);

    for (int kb = 0; kb < Kd; kb += 16) {
        __syncthreads();
        As[sk8 + 0][sr] = a0.x; As[sk8 + 1][sr] = a0.y;
        As[sk8 + 2][sr] = a0.z; As[sk8 + 3][sr] = a0.w;
        As[sk8 + 4][sr] = a1.x; As[sk8 + 5][sr] = a1.y;
        As[sk8 + 6][sr] = a1.z; As[sk8 + 7][sr] = a1.w;
        *(float4*)&Bs[bkr][bc8]     = b0;
        *(float4*)&Bs[bkr][bc8 + 4] = b1;
        __syncthreads();
        if (kb + 16 < Kd) {
            a0 = *(const float4*)(Ap + kb + 16);
            a1 = *(const float4*)(Ap + kb + 20);
            b0 = *(const float4*)(Bp + (size_t)(kb + 16) * ldb);
            b1 = *(const float4*)(Bp + (size_t)(kb + 16) * ldb + 4);
        }
#pragma unroll
        for (int kk = 0; kk < 16; ++kk) {
            float a[8], b[8];
            *(float4*)&a[0] = *(const float4*)&As[kk][ty * 8];
            *(float4*)&a[4] = *(const float4*)&As[kk][ty * 8 + 4];
            *(float4*)&b[0] = *(const float4*)&Bs[kk][tx * 8];
            *(float4*)&b[4] = *(const float4*)&Bs[kk][tx * 8 + 4];
#pragma unroll
            for (int i = 0; i < 8; ++i)
#pragma unroll
                for (int j = 0; j < 8; ++j)
                    acc[i][j] += a[i] * b[j];
        }
    }

    float bb[8];
#pragma unroll
    for (int j = 0; j < 8; ++j) bb[j] = bias[cb + tx * 8 + j];

#pragma unroll
    for (int i = 0; i < 8; ++i) {
        const size_t off = (size_t)(rb + ty * 8 + i) * ldc + cb + tx * 8;
        *(float4*)&C[off]     = make_float4(acc[i][0] + bb[0], acc[i][1] + bb[1],
                                            acc[i][2] + bb[2], acc[i][3] + bb[3]);
        *(float4*)&C[off + 4] = make_float4(acc[i][4] + bb[4], acc[i][5] + bb[5],
                                            acc[i][6] + bb[6], acc[i][7] + bb[7]);
    }
}

// ---------------------------------------------------------------------------
// split fp32 rows [nrows][256] into hi/lo bf16 planes (FRAGMENT-PACKED) and
// simultaneously emit per-row squared norms (fused rowsq).
//   elem(row,k) -> ((row>>4)*8 + (k>>5))*512 + ((k>>3)&3)*128 + (row&15)*8 + (k&7)
__global__ __launch_bounds__(256)
void split_pack(const float* __restrict__ X, u16* __restrict__ hi,
                u16* __restrict__ lo, float* __restrict__ s2)
{
    const int tid = (blockIdx.x << 8) + threadIdx.x;
    const int row = tid >> 5;
    const int kb  = (tid & 31) << 3;
    const float4 v0 = *(const float4*)(X + ((size_t)row << 8) + kb);
    const float4 v1 = *(const float4*)(X + ((size_t)row << 8) + kb + 4);
    const float f[8] = {v0.x, v0.y, v0.z, v0.w, v1.x, v1.y, v1.z, v1.w};
    us8 hv, lv;
    float s = 0.0f;
#pragma unroll
    for (int e = 0; e < 8; ++e) {
        const u16 h = f2bf_rne(f[e]);
        const float hf = __uint_as_float((u32)h << 16);
        hv[e] = h;
        lv[e] = f2bf_rne(f[e] - hf);
        s += f[e] * f[e];
    }
    const size_t off = ((size_t)(row >> 4) * 8 + (kb >> 5)) * 512
                     + (size_t)((kb >> 3) & 3) * 128 + ((row & 15) << 3);
    *(us8*)(hi + off) = hv;
    *(us8*)(lo + off) = lv;
#pragma unroll
    for (int m = 1; m <= 16; m <<= 1) s += __shfl_xor(s, m, 64);
    if ((threadIdx.x & 31) == 0) s2[row] = s;
}

// ---------------------------------------------------------------------------
// pack W_out [K=256][N=1024] (row-major) into fragment-packed bf16 hi/lo planes
// indexed by (n, k)
__global__ __launch_bounds__(256)
void pack_wout(const float* __restrict__ W, u16* __restrict__ hi, u16* __restrict__ lo)
{
    const int tid = (blockIdx.x << 8) + threadIdx.x;
    const int n  = tid >> 5;
    const int kb = (tid & 31) << 3;
    us8 hv, lv;
#pragma unroll
    for (int e = 0; e < 8; ++e) {
        const float f = W[(size_t)(kb + e) * DIN + n];
        const u16 h = f2bf_rne(f);
        hv[e] = h;
        lv[e] = f2bf_rne(f - __uint_as_float((u32)h << 16));
    }
    const size_t off = ((size_t)(n >> 4) * 8 + (kb >> 5)) * 512
                     + (size_t)((kb >> 3) & 3) * 128 + ((n & 15) << 3);
    *(us8*)(hi + off) = hv;
    *(us8*)(lo + off) = lv;
}

// ---------------------------------------------------------------------------
// bf16x3 MFMA distance GEMM + per-(row, 64-col-slice) argmin key.
// 128x128 tile, 4 waves (2x2). DOUBLE-BUFFERED LDS with early-issue staging:
// global_load_lds for tile ks+1 is issued BEFORE the ds_read+MFMA of tile ks,
// so load latency hides under ~240-700 cyc of MFMA; one barrier per K-step.
// acc init = -e2/2 => acc ends as s = dot - e2/2; argmin d == argmax s.
__global__ __launch_bounds__(256)
void score_mfma(const u16* __restrict__ zh, const u16* __restrict__ zl,
                const u16* __restrict__ eh, const u16* __restrict__ el,
                const float* __restrict__ e2, u64* __restrict__ partial)
{
    __shared__ u16 smem[2][4][8][512];   // 64 KB: [dbuf][plane Zh,Zl,Eh,El][frag][512]
    const int t = threadIdx.x;
    const int w = t >> 6, lane = t & 63;
    const int wr = w >> 1, wc = w & 1;
    const int rb = blockIdx.x << 7, cb = blockIdx.y << 7;
    const u32 lane8 = (u32)lane << 3;
    const int g = lane >> 4, li = lane & 15;

    // global element offsets of the two 1KB chunks this wave stages per plane
    const u32 zc0 = (u32)((rb >> 4) + w)     * 4096 + lane8;
    const u32 zc1 = (u32)((rb >> 4) + 4 + w) * 4096 + lane8;
    const u32 ec0 = (u32)((cb >> 4) + w)     * 4096 + lane8;
    const u32 ec1 = (u32)((cb >> 4) + 4 + w) * 4096 + lane8;

    int codes[4];
    float e2v[4];
#pragma unroll
    for (int j = 0; j < 4; ++j) {
        codes[j] = cb + wc * 64 + j * 16 + li;
        e2v[j] = e2[codes[j]];
    }

    f32x4 acc[4][4];
#pragma unroll
    for (int i = 0; i < 4; ++i)
#pragma unroll
        for (int j = 0; j < 4; ++j) {
            const float v = -0.5f * e2v[j];
            acc[i][j] = (f32x4){v, v, v, v};
        }

    // prologue: issue tile 0 into buffer 0
    GLOAD16(zh + zc0, &smem[0][0][w][0]);  GLOAD16(zh + zc1, &smem[0][0][4 + w][0]);
    GLOAD16(zl + zc0, &smem[0][1][w][0]);  GLOAD16(zl + zc1, &smem[0][1][4 + w][0]);
    GLOAD16(eh + ec0, &smem[0][2][w][0]);  GLOAD16(eh + ec1, &smem[0][2][4 + w][0]);
    GLOAD16(el + ec0, &smem[0][3][w][0]);  GLOAD16(el + ec1, &smem[0][3][4 + w][0]);

    int b = 0;
    for (int ks = 0; ks < 8; ++ks) {
        __syncthreads();      // drains own vmcnt -> tile ks resident; syncs prev readers
        if (ks < 7) {         // early-issue next tile into the other buffer
            const u32 ko = (u32)(ks + 1) << 9;
            const int nb = b ^ 1;
            GLOAD16(zh + zc0 + ko, &smem[nb][0][w][0]);  GLOAD16(zh + zc1 + ko, &smem[nb][0][4 + w][0]);
            GLOAD16(zl + zc0 + ko, &smem[nb][1][w][0]);  GLOAD16(zl + zc1 + ko, &smem[nb][1][4 + w][0]);
            GLOAD16(eh + ec0 + ko, &smem[nb][2][w][0]);  GLOAD16(eh + ec1 + ko, &smem[nb][2][4 + w][0]);
            GLOAD16(el + ec0 + ko, &smem[nb][3][w][0]);  GLOAD16(el + ec1 + ko, &smem[nb][3][4 + w][0]);
        }

        bf16x8 ah[4], al[4], bh[4], bl[4];
#pragma unroll
        for (int i = 0; i < 4; ++i) {
            ah[i] = *(const bf16x8*)&smem[b][0][wr * 4 + i][lane8];
            al[i] = *(const bf16x8*)&smem[b][1][wr * 4 + i][lane8];
            bh[i] = *(const bf16x8*)&smem[b][2][wc * 4 + i][lane8];
            bl[i] = *(const bf16x8*)&smem[b][3][wc * 4 + i][lane8];
        }
#pragma unroll
        for (int i = 0; i < 4; ++i)
#pragma unroll
            for (int j = 0; j < 4; ++j) {
                acc[i][j] = __builtin_amdgcn_mfma_f32_16x16x32_bf16(ah[i], bh[j], acc[i][j], 0, 0, 0);
                acc[i][j] = __builtin_amdgcn_mfma_f32_16x16x32_bf16(ah[i], bl[j], acc[i][j], 0, 0, 0);
                acc[i][j] = __builtin_amdgcn_mfma_f32_16x16x32_bf16(al[i], bh[j], acc[i][j], 0, 0, 0);
            }
        b ^= 1;
    }

    // epilogue: D row = (lane>>4)*4 + r, col = lane&15 (verified layout)
    const int slot = (blockIdx.y << 1) + wc;

#pragma unroll
    for (int i = 0; i < 4; ++i) {
#pragma unroll
        for (int r = 0; r < 4; ++r) {
            const int row = rb + wr * 64 + i * 16 + g * 4 + r;
            const float s0 = acc[i][0][r], s1 = acc[i][1][r];
            const float s2s = acc[i][2][r], s3 = acc[i][3][r];
            const float mm = fmaxf(fmaxf(s0, s1), fmaxf(s2s, s3));
            const u32 cj = (mm == s0) ? (u32)codes[0]
                         : (mm == s1) ? (u32)codes[1]
                         : (mm == s2s) ? (u32)codes[2] : (u32)codes[3];
            u64 key = ((u64)ford(-mm) << 32) | cj;
#pragma unroll
            for (int m = 1; m <= 8; m <<= 1) {       // reduce across 16-lane group
                const u64 o = shfl_xor_u64(key, m);
                key = (o < key) ? o : key;
            }
            if (li == 0) partial[((size_t)row << 8) + slot] = key;
        }
    }
}

// ---------------------------------------------------------------------------
// top-2 of 256 partial keys per row, exact fp32 re-check of both candidates,
// then write bneck / qidx / reg_z. One wave per row.
__global__ __launch_bounds__(256)
void finalize2(const u64* __restrict__ partial, const float* __restrict__ Z,
               const float* __restrict__ E, const float* __restrict__ z2,
               const float* __restrict__ e2,
               float* __restrict__ bneck, float* __restrict__ regz,
               int* __restrict__ qidx)
{
    const int t = threadIdx.x;
    const int row = (blockIdx.x << 2) + (t >> 6);
    const int lane = t & 63;
    const u64* p = partial + ((size_t)row << 8);

    u64 a1 = ~0ull, a2 = ~0ull;
#pragma unroll
    for (int q = 0; q < 4; ++q) {
        const u64 k = p[(q << 6) + lane];
        if (k < a1) { a2 = a1; a1 = k; }
        else if (k < a2) { a2 = k; }
    }
#pragma unroll
    for (int m = 1; m <= 32; m <<= 1) {   // butterfly top-2 merge
        const u64 b1 = shfl_xor_u64(a1, m);
        const u64 b2 = shfl_xor_u64(a2, m);
        if (b1 < a1) { a2 = (a1 < b2) ? a1 : b2; a1 = b1; }
        else         { a2 = (a2 < b1) ? a2 : b1; }
    }
    const u32 i1 = (u32)a1 & (KCODES - 1);
    const u32 i2 = (u32)a2 & (KCODES - 1);

    // exact fp32 distances for both candidates (mirrors np order of ops)
    const float4 zv  = *(const float4*)(Z + ((size_t)row << 8) + (lane << 2));
    const float4 c1v = *(const float4*)(E + ((size_t)i1 << 8) + (lane << 2));
    const float4 c2v = *(const float4*)(E + ((size_t)i2 << 8) + (lane << 2));
    float s1 = zv.x * c1v.x + zv.y * c1v.y + zv.z * c1v.z + zv.w * c1v.w;
    float s2 = zv.x * c2v.x + zv.y * c2v.y + zv.z * c2v.z + zv.w * c2v.w;
#pragma unroll
    for (int m = 32; m >= 1; m >>= 1) {
        s1 += __shfl_xor(s1, m, 64);
        s2 += __shfl_xor(s2, m, 64);
    }
    const float zz = z2[row];
    const float d1 = (zz + e2[i1]) - 2.0f * s1;
    const float d2 = (zz + e2[i2]) - 2.0f * s2;
    u32 win = i1;
    if (d2 < d1 || (d2 == d1 && i2 < i1)) win = i2;

    if (lane == 0) { qidx[row] = (int)win; bneck[row] = (float)win; }
    const float4 vw = *(const float4*)(E + ((size_t)win << 8) + (lane << 2));
    *(float4*)(regz + ((size_t)row << 8) + (lane << 2)) = vw;
}

// ---------------------------------------------------------------------------
// emb_out = emb @ W_out + b_out via bf16x3 MFMA. M=16384, N=1024, K=256.
// Same double-buffered early-issue K-loop as score_mfma.
__global__ __launch_bounds__(256)
void embout_mfma(const u16* __restrict__ ah_p, const u16* __restrict__ al_p,
                 const u16* __restrict__ bh_p, const u16* __restrict__ bl_p,
                 const float* __restrict__ bias, float* __restrict__ C)
{
    __shared__ u16 smem[2][4][8][512];
    const int t = threadIdx.x;
    const int w = t >> 6, lane = t & 63;
    const int wr = w >> 1, wc = w & 1;
    const int rb = blockIdx.x << 7, cb = blockIdx.y << 7;
    const u32 lane8 = (u32)lane << 3;
    const int g = lane >> 4, li = lane & 15;

    const u32 ac0 = (u32)((rb >> 4) + w)     * 4096 + lane8;
    const u32 ac1 = (u32)((rb >> 4) + 4 + w) * 4096 + lane8;
    const u32 bc0 = (u32)((cb >> 4) + w)     * 4096 + lane8;
    const u32 bc1 = (u32)((cb >> 4) + 4 + w) * 4096 + lane8;

    f32x4 acc[4][4];
#pragma unroll
    for (int i = 0; i < 4; ++i)
#pragma unroll
        for (int j = 0; j < 4; ++j) acc[i][j] = (f32x4){0.f, 0.f, 0.f, 0.f};

    GLOAD16(ah_p + ac0, &smem[0][0][w][0]);  GLOAD16(ah_p + ac1, &smem[0][0][4 + w][0]);
    GLOAD16(al_p + ac0, &smem[0][1][w][0]);  GLOAD16(al_p + ac1, &smem[0][1][4 + w][0]);
    GLOAD16(bh_p + bc0, &smem[0][2][w][0]);  GLOAD16(bh_p + bc1, &smem[0][2][4 + w][0]);
    GLOAD16(bl_p + bc0, &smem[0][3][w][0]);  GLOAD16(bl_p + bc1, &smem[0][3][4 + w][0]);

    int b = 0;
    for (int ks = 0; ks < 8; ++ks) {
        __syncthreads();
        if (ks < 7) {
            const u32 ko = (u32)(ks + 1) << 9;
            const int nb = b ^ 1;
            GLOAD16(ah_p + ac0 + ko, &smem[nb][0][w][0]);  GLOAD16(ah_p + ac1 + ko, &smem[nb][0][4 + w][0]);
            GLOAD16(al_p + ac0 + ko, &smem[nb][1][w][0]);  GLOAD16(al_p + ac1 + ko, &smem[nb][1][4 + w][0]);
            GLOAD16(bh_p + bc0 + ko, &smem[nb][2][w][0]);  GLOAD16(bh_p + bc1 + ko, &smem[nb][2][4 + w][0]);
            GLOAD16(bl_p + bc0 + ko, &smem[nb][3][w][0]);  GLOAD16(bl_p + bc1 + ko, &smem[nb][3][4 + w][0]);
        }

        bf16x8 ah[4], al[4], bh[4], bl[4];
#pragma unroll
        for (int i = 0; i < 4; ++i) {
            ah[i] = *(const bf16x8*)&smem[b][0][wr * 4 + i][lane8];
            al[i] = *(const bf16x8*)&smem[b][1][wr * 4 + i][lane8];
            bh[i] = *(const bf16x8*)&smem[b][2][wc * 4 + i][lane8];
            bl[i] = *(const bf16x8*)&smem[b][3][wc * 4 + i][lane8];
        }
#pragma unroll
        for (int i = 0; i < 4; ++i)
#pragma unroll
            for (int j = 0; j < 4; ++j) {
                acc[i][j] = __builtin_amdgcn_mfma_f32_16x16x32_bf16(ah[i], bh[j], acc[i][j], 0, 0, 0);
                acc[i][j] = __builtin_amdgcn_mfma_f32_16x16x32_bf16(ah[i], bl[j], acc[i][j], 0, 0, 0);
                acc[i][j] = __builtin_amdgcn_mfma_f32_16x16x32_bf16(al[i], bh[j], acc[i][j], 0, 0, 0);
            }
        b ^= 1;
    }

    float bv[4];
#pragma unroll
    for (int j = 0; j < 4; ++j) bv[j] = bias[cb + wc * 64 + j * 16 + li];

#pragma unroll
    for (int i = 0; i < 4; ++i)
#pragma unroll
        for (int j = 0; j < 4; ++j) {
            const int col = cb + wc * 64 + j * 16 + li;
#pragma unroll
            for (int r = 0; r < 4; ++r) {
                const int m = rb + wr * 64 + i * 16 + g * 4 + r;
                C[(size_t)m * DIN + col] = acc[i][j][r] + bv[j];
            }
        }
}

// x_hat[row] = emb_out[qidx[row]] — one block per row, float4 copy
__global__ __launch_bounds__(256)
void gather_rows(const int* __restrict__ qidx, const float* __restrict__ S,
                 float* __restrict__ D)
{
    const int row = blockIdx.x;
    const int q = qidx[row] & (KCODES - 1);
    const float4 v = *(const float4*)(S + ((size_t)q << 10) + (threadIdx.x << 2));
    *(float4*)(D + ((size_t)row << 10) + (threadIdx.x << 2)) = v;
}

// ---------------------------------------------------------------------------
// fallback: x_hat = emb[qidx[row]] @ W_out(f32) + b_out (unchanged, verified)
__global__ __launch_bounds__(256)
void xhat_gemm(const int* __restrict__ qidx, const float* __restrict__ E,
               const float* __restrict__ B, const float* __restrict__ bias,
               float* __restrict__ C)
{
    __shared__ float As[16][132];
    __shared__ float Bs[16][132];
    const int t = threadIdx.x;
    const int w = t >> 6, lane = t & 63;
    const int tx = (lane & 7) | ((w & 1) << 3);
    const int ty = ((lane >> 3) & 7) | ((w >> 1) << 3);
    const int rb = blockIdx.x << 7;
    const int cb = blockIdx.y << 7;

    const int sr  = t >> 1;
    const int sk8 = (t & 1) << 3;
    const int bkr = t >> 4;
    const int bc8 = (t & 15) << 3;

    const int aidx = qidx[rb + sr] & (KCODES - 1);
    const float* Ap = E + (size_t)aidx * DB + sk8;
    const float* Bp = B + (size_t)bkr * DIN + cb + bc8;

    float acc[8][8];
#pragma unroll
    for (int i = 0; i < 8; ++i)
#pragma unroll
        for (int j = 0; j < 8; ++j) acc[i][j] = 0.0f;

    float4 a0 = *(const float4*)Ap;
    float4 a1 = *(const float4*)(Ap + 4);
    float4 b0 = *(const float4*)Bp;
    float4 b1 = *(const float4*)(Bp + 4);

    for (int kb = 0; kb < DB; kb += 16) {
        __syncthreads();
        As[sk8 + 0][sr] = a0.x; As[sk8 + 1][sr] = a0.y;
        As[sk8 + 2][sr] = a0.z; As[sk8 + 3][sr] = a0.w;
        As[sk8 + 4][sr] = a1.x; As[sk8 + 5][sr] = a1.y;
        As[sk8 + 6][sr] = a1.z; As[sk8 + 7][sr] = a1.w;
        *(float4*)&Bs[bkr][bc8]     = b0;
        *(float4*)&Bs[bkr][bc8 + 4] = b1;
        __syncthreads();
        if (kb + 16 < DB) {
            a0 = *(const float4*)(Ap + kb + 16);
            a1 = *(const float4*)(Ap + kb + 20);
            b0 = *(const float4*)(Bp + (size_t)(kb + 16) * DIN);
            b1 = *(const float4*)(Bp + (size_t)(kb + 16) * DIN + 4);
        }
#pragma unroll
        for (int kk = 0; kk < 16; ++kk) {
            float a[8], b[8];
            *(float4*)&a[0] = *(const float4*)&As[kk][ty * 8];
            *(float4*)&a[4] = *(const float4*)&As[kk][ty * 8 + 4];
            *(float4*)&b[0] = *(const float4*)&Bs[kk][tx * 8];
            *(float4*)&b[4] = *(const float4*)&Bs[kk][tx * 8 + 4];
#pragma unroll
            for (int i = 0; i < 8; ++i)
#pragma unroll
                for (int j = 0; j < 8; ++j)
                    acc[i][j] += a[i] * b[j];
        }
    }

    float bb[8];
#pragma unroll
    for (int j = 0; j < 8; ++j) bb[j] = bias[cb + tx * 8 + j];

#pragma unroll
    for (int i = 0; i < 8; ++i) {
        const size_t off = (size_t)(rb + ty * 8 + i) * DIN + cb + tx * 8;
        *(float4*)&C[off]     = make_float4(acc[i][0] + bb[0], acc[i][1] + bb[1],
                                            acc[i][2] + bb[2], acc[i][3] + bb[3]);
        *(float4*)&C[off + 4] = make_float4(acc[i][4] + bb[4], acc[i][5] + bb[5],
                                            acc[i][6] + bb[6], acc[i][7] + bb[7]);
    }
}

extern "C" void kernel_launch(void* const* d_in, const int* in_sizes, int n_in,
                              void* d_out, int out_size, void* d_ws, size_t ws_size,
                              hipStream_t stream)
{
    const float* x        = (const float*)d_in[0];
    const float* W_in     = (const float*)d_in[1];
    const float* b_in     = (const float*)d_in[2];
    const float* W_out    = (const float*)d_in[3];
    const float* b_out    = (const float*)d_in[4];
    const float* codebook = (const float*)d_in[5];
    const float* W_proj   = (const float*)d_in[6];
    const float* b_proj   = (const float*)d_in[7];

    // fp32 output layout, return order (x_hat, bneck, z, emb, reg_z)
    float* out   = (float*)d_out;
    float* xhat  = out;                   // 33,554,432 f  (written last)
    float* bneck = out + 33554432;        //     32,768 f
    float* z     = out + 33587200;        //  8,388,608 f
    float* emb   = out + 41975808;        //  4,194,304 f
    float* regz  = out + 46170112;        //  8,388,608 f  (written by finalize2)

    // scratch carved from not-yet-written output regions:
    //  - xhat region (134.2 MB): partial keys (64 MB) + eh/el packs (16.8 MB),
    //    all dead before xhat is written (by gather_rows or xhat_gemm).
    //  - regz region (33.55 MB): zh/zl packs, dead before finalize2 writes regz.
    char* outc = (char*)d_out;
    u64* partial = (u64*)outc;                        // 67,108,864 B
    u16* eh = (u16*)(outc + 67108864);                //  8,388,608 B
    u16* el = (u16*)(outc + 75497472);                //  8,388,608 B
    u16* zh = (u16*)(outc + 184680448);               // 16,777,216 B (regz start)
    u16* zl = (u16*)(outc + 201457664);               // 16,777,216 B

    // d_ws: small buffers + (if capacity) emb_out fast path
    char* ws = (char*)d_ws;
    float* e2   = (float*)ws;                 //  64 KB
    float* z2   = (float*)(ws + 65536);       // 128 KB
    int*   qidx = (int*)  (ws + 196608);      // 128 KB
    u16*   whh     = (u16*)  (ws + 327680);   // 512 KB
    u16*   whl     = (u16*)  (ws + 851968);   // 512 KB
    float* emb_out = (float*)(ws + 1376256);  // 67,108,864 B
    const bool fast_xhat = (ws_size >= (size_t)1376256 + 67108864);

    // 1. emb = codebook @ W_proj + b_proj
    sgemm_f32<<<dim3(128, 2), 256, 0, stream>>>(codebook, DB, W_proj, DB, b_proj,
                                                emb, DB, DB);
    // 2. split emb -> eh/el packs + e2 norms (fused)
    split_pack<<<KCODES / 8, 256, 0, stream>>>(emb, eh, el, e2);
    if (fast_xhat) {
        // 3. W_out -> fragment-packed bf16 planes; emb_out = emb @ W_out + b_out
        pack_wout<<<DIN / 8, 256, 0, stream>>>(W_out, whh, whl);
        embout_mfma<<<dim3(KCODES / 128, DIN / 128), 256, 0, stream>>>(
            eh, el, whh, whl, b_out, emb_out);
    }
    // 4. z = x @ W_in + b_in
    sgemm_f32<<<dim3(256, 2), 256, 0, stream>>>(x, DIN, W_in, DB, b_in,
                                                z, DB, DIN);
    // 5. split z -> zh/zl packs + z2 norms (fused)
    split_pack<<<M_ROWS / 8, 256, 0, stream>>>(z, zh, zl, z2);
    // 6. bf16x3 MFMA score GEMM + per-slice argmax-s keys (no atomics, no init)
    score_mfma<<<dim3(M_ROWS / 128, KCODES / 128), 256, 0, stream>>>(
        zh, zl, eh, el, e2, partial);
    // 7. top-2 + exact fp32 recheck; write bneck / qidx / reg_z
    finalize2<<<M_ROWS / 4, 256, 0, stream>>>(partial, z, emb, z2, e2,
                                              bneck, regz, qidx);
    // 8. x_hat
    if (fast_xhat) {
        gather_rows<<<M_ROWS, 256, 0, stream>>>(qidx, emb_out, xhat);
    } else {
        xhat_gemm<<<dim3(256, 8), 256, 0, stream>>>(qidx, emb, W_out, b_out, xhat);
    }
}

// Round 5
// 1432.973 us; speedup vs baseline: 1.0249x; 1.0249x over previous
//
#include <hip/hip_runtime.h>

typedef unsigned int u32;
typedef unsigned long long u64;
typedef unsigned short u16;

#define M_ROWS 32768
#define DB 256
#define DIN 1024
#define KCODES 16384

typedef __attribute__((ext_vector_type(8))) short bf16x8;   // 8 bf16 = 4 VGPR (MFMA A/B frag)
typedef __attribute__((ext_vector_type(4))) float f32x4;    // MFMA C/D frag
typedef __attribute__((ext_vector_type(8))) unsigned short us8;

// async global->LDS, 16B per lane; LDS dst = wave-uniform base + lane*16
#define GLOAD16(gp, lp) __builtin_amdgcn_global_load_lds( \
    (const __attribute__((address_space(1))) unsigned int*)(gp), \
    (__attribute__((address_space(3))) unsigned int*)(lp), 16, 0, 0)

// order-preserving fp32 -> u32 (finite values)
__device__ __forceinline__ u32 ford(float f) {
    u32 u = __float_as_uint(f);
    return (u & 0x80000000u) ? ~u : (u | 0x80000000u);
}
__device__ __forceinline__ u64 shfl_xor_u64(u64 v, int m) {
    u32 lo = (u32)v, hi = (u32)(v >> 32);
    lo = (u32)__shfl_xor((int)lo, m, 64);
    hi = (u32)__shfl_xor((int)hi, m, 64);
    return ((u64)hi << 32) | lo;
}
__device__ __forceinline__ u16 f2bf_rne(float f) {
    const u32 u = __float_as_uint(f);
    return (u16)((u + 0x7FFFu + ((u >> 16) & 1u)) >> 16);
}

// ---------------------------------------------------------------------------
// C(f32)[M,N] = A(f32)[M,Kd] @ B(f32)[Kd,N] + bias(f32)[N]
// block tile 128x128, BK=16, thread tile 8x8, 256 threads. (unchanged, verified)
__global__ __launch_bounds__(256)
void sgemm_f32(const float* __restrict__ A, int lda,
               const float* __restrict__ B, int ldb,
               const float* __restrict__ bias,
               float* __restrict__ C, int ldc, int Kd)
{
    __shared__ float As[16][132];
    __shared__ float Bs[16][132];
    const int t = threadIdx.x;
    const int w = t >> 6, lane = t & 63;
    const int tx = (lane & 7) | ((w & 1) << 3);
    const int ty = ((lane >> 3) & 7) | ((w >> 1) << 3);
    const int rb = blockIdx.x << 7;
    const int cb = blockIdx.y << 7;

    const int sr  = t >> 1;
    const int sk8 = (t & 1) << 3;
    const int bkr = t >> 4;
    const int bc8 = (t & 15) << 3;

    const float* Ap = A + (size_t)(rb + sr) * lda + sk8;
    const float* Bp = B + (size_t)bkr * ldb + cb + bc8;

    float acc[8][8];
#pragma unroll
    for (int i = 0; i < 8; ++i)
#pragma unroll
        for (int j = 0; j < 8; ++j) acc[i][j] = 0.0f;

    float4 a0 = *(const float4*)Ap;
    float4 a1 = *(const float4*)(Ap + 4);
    float4 b0 = *(const float4*)Bp;
    float4 b1 = *(const float4*)(Bp + 4);

    for (int kb = 0; kb < Kd; kb += 16) {
        __syncthreads();
        As[sk8 + 0][sr] = a0.x; As[sk8 + 1][sr] = a0.y;
        As[sk8 + 2][sr] = a0.z; As[sk8 + 3][sr] = a0.w;
        As[sk8 + 4][sr] = a1.x; As[sk8 + 5][sr] = a1.y;
        As[sk8 + 6][sr] = a1.z; As[sk8 + 7][sr] = a1.w;
        *(float4*)&Bs[bkr][bc8]     = b0;
        *(float4*)&Bs[bkr][bc8 + 4] = b1;
        __syncthreads();
        if (kb + 16 < Kd) {
            a0 = *(const float4*)(Ap + kb + 16);
            a1 = *(const float4*)(Ap + kb + 20);
            b0 = *(const float4*)(Bp + (size_t)(kb + 16) * ldb);
            b1 = *(const float4*)(Bp + (size_t)(kb + 16) * ldb + 4);
        }
#pragma unroll
        for (int kk = 0; kk < 16; ++kk) {
            float a[8], b[8];
            *(float4*)&a[0] = *(const float4*)&As[kk][ty * 8];
            *(float4*)&a[4] = *(const float4*)&As[kk][ty * 8 + 4];
            *(float4*)&b[0] = *(const float4*)&Bs[kk][tx * 8];
            *(float4*)&b[4] = *(const float4*)&Bs[kk][tx * 8 + 4];
#pragma unroll
            for (int i = 0; i < 8; ++i)
#pragma unroll
                for (int j = 0; j < 8; ++j)
                    acc[i][j] += a[i] * b[j];
        }
    }

    float bb[8];
#pragma unroll
    for (int j = 0; j < 8; ++j) bb[j] = bias[cb + tx * 8 + j];

#pragma unroll
    for (int i = 0; i < 8; ++i) {
        const size_t off = (size_t)(rb + ty * 8 + i) * ldc + cb + tx * 8;
        *(float4*)&C[off]     = make_float4(acc[i][0] + bb[0], acc[i][1] + bb[1],
                                            acc[i][2] + bb[2], acc[i][3] + bb[3]);
        *(float4*)&C[off + 4] = make_float4(acc[i][4] + bb[4], acc[i][5] + bb[5],
                                            acc[i][6] + bb[6], acc[i][7] + bb[7]);
    }
}

// ---------------------------------------------------------------------------
// split fp32 rows [nrows][256] into hi/lo bf16 planes (FRAGMENT-PACKED) and
// simultaneously emit per-row squared norms (fused rowsq).
//   elem(row,k) -> ((row>>4)*8 + (k>>5))*512 + ((k>>3)&3)*128 + (row&15)*8 + (k&7)
__global__ __launch_bounds__(256)
void split_pack(const float* __restrict__ X, u16* __restrict__ hi,
                u16* __restrict__ lo, float* __restrict__ s2)
{
    const int tid = (blockIdx.x << 8) + threadIdx.x;
    const int row = tid >> 5;
    const int kb  = (tid & 31) << 3;
    const float4 v0 = *(const float4*)(X + ((size_t)row << 8) + kb);
    const float4 v1 = *(const float4*)(X + ((size_t)row << 8) + kb + 4);
    const float f[8] = {v0.x, v0.y, v0.z, v0.w, v1.x, v1.y, v1.z, v1.w};
    us8 hv, lv;
    float s = 0.0f;
#pragma unroll
    for (int e = 0; e < 8; ++e) {
        const u16 h = f2bf_rne(f[e]);
        const float hf = __uint_as_float((u32)h << 16);
        hv[e] = h;
        lv[e] = f2bf_rne(f[e] - hf);
        s += f[e] * f[e];
    }
    const size_t off = ((size_t)(row >> 4) * 8 + (kb >> 5)) * 512
                     + (size_t)((kb >> 3) & 3) * 128 + ((row & 15) << 3);
    *(us8*)(hi + off) = hv;
    *(us8*)(lo + off) = lv;
#pragma unroll
    for (int m = 1; m <= 16; m <<= 1) s += __shfl_xor(s, m, 64);
    if ((threadIdx.x & 31) == 0) s2[row] = s;
}

// ---------------------------------------------------------------------------
// pack W_out [K=256][N=1024] (row-major) into fragment-packed bf16 hi/lo planes
// indexed by (n, k)
__global__ __launch_bounds__(256)
void pack_wout(const float* __restrict__ W, u16* __restrict__ hi, u16* __restrict__ lo)
{
    const int tid = (blockIdx.x << 8) + threadIdx.x;
    const int n  = tid >> 5;
    const int kb = (tid & 31) << 3;
    us8 hv, lv;
#pragma unroll
    for (int e = 0; e < 8; ++e) {
        const float f = W[(size_t)(kb + e) * DIN + n];
        const u16 h = f2bf_rne(f);
        hv[e] = h;
        lv[e] = f2bf_rne(f - __uint_as_float((u32)h << 16));
    }
    const size_t off = ((size_t)(n >> 4) * 8 + (kb >> 5)) * 512
                     + (size_t)((kb >> 3) & 3) * 128 + ((n & 15) << 3);
    *(us8*)(hi + off) = hv;
    *(us8*)(lo + off) = lv;
}

// ---------------------------------------------------------------------------
// bf16x3 MFMA distance GEMM + per-(row, 64-col-slice) argmin key.
// 128x128 tile, 4 waves (2x2). T4 counted-vmcnt double-buffered pipeline:
// tiles ks and ks+1 always in flight; per K-step: vmcnt(8) [NOT 0] -> s_barrier
// -> ds_read+MFMA -> s_barrier -> issue tile ks+2 into freed buffer.
// No __syncthreads in the loop (it would drain vmcnt(0) and kill the pipeline).
// acc init = -e2/2 => acc ends as s = dot - e2/2; argmin d == argmax s.
__global__ __launch_bounds__(256)
void score_mfma(const u16* __restrict__ zh, const u16* __restrict__ zl,
                const u16* __restrict__ eh, const u16* __restrict__ el,
                const float* __restrict__ e2, u64* __restrict__ partial)
{
    __shared__ u16 smem[2][4][8][512];   // 64 KB: [dbuf][plane Zh,Zl,Eh,El][frag][512]
    const int t = threadIdx.x;
    const int w = t >> 6, lane = t & 63;
    const int wr = w >> 1, wc = w & 1;
    const int rb = blockIdx.x << 7, cb = blockIdx.y << 7;
    const u32 lane8 = (u32)lane << 3;
    const int g = lane >> 4, li = lane & 15;

    // global element offsets of the two 1KB chunks this wave stages per plane
    const u32 zc0 = (u32)((rb >> 4) + w)     * 4096 + lane8;
    const u32 zc1 = (u32)((rb >> 4) + 4 + w) * 4096 + lane8;
    const u32 ec0 = (u32)((cb >> 4) + w)     * 4096 + lane8;
    const u32 ec1 = (u32)((cb >> 4) + 4 + w) * 4096 + lane8;

    int codes[4];
    float e2v[4];
#pragma unroll
    for (int j = 0; j < 4; ++j) {
        codes[j] = cb + wc * 64 + j * 16 + li;
        e2v[j] = e2[codes[j]];
    }

    f32x4 acc[4][4];
#pragma unroll
    for (int i = 0; i < 4; ++i)
#pragma unroll
        for (int j = 0; j < 4; ++j) {
            const float v = -0.5f * e2v[j];
            acc[i][j] = (f32x4){v, v, v, v};
        }

#define STAGE(B, KO) do { \
    GLOAD16(zh + zc0 + (KO), &smem[B][0][w][0]);  GLOAD16(zh + zc1 + (KO), &smem[B][0][4 + w][0]); \
    GLOAD16(zl + zc0 + (KO), &smem[B][1][w][0]);  GLOAD16(zl + zc1 + (KO), &smem[B][1][4 + w][0]); \
    GLOAD16(eh + ec0 + (KO), &smem[B][2][w][0]);  GLOAD16(eh + ec1 + (KO), &smem[B][2][4 + w][0]); \
    GLOAD16(el + ec0 + (KO), &smem[B][3][w][0]);  GLOAD16(el + ec1 + (KO), &smem[B][3][4 + w][0]); \
} while (0)

    // drain the e2 loads so this wave's vmcnt below counts ONLY staging loads
    asm volatile("s_waitcnt vmcnt(0)" ::: "memory");
    __builtin_amdgcn_sched_barrier(0);

    // prologue: tiles 0 and 1 in flight (8 loads each, per wave)
    STAGE(0, 0u);
    STAGE(1, 512u);

#pragma unroll
    for (int ks = 0; ks < 8; ++ks) {
        // wait for tile ks (leave tile ks+1's 8 loads in flight)
        if (ks < 7) { asm volatile("s_waitcnt vmcnt(8)" ::: "memory"); }
        else        { asm volatile("s_waitcnt vmcnt(0)" ::: "memory"); }
        __builtin_amdgcn_sched_barrier(0);
        __builtin_amdgcn_s_barrier();          // all waves' tile-ks writes visible
        asm volatile("" ::: "memory");
        __builtin_amdgcn_sched_barrier(0);

        const int b = ks & 1;                  // static after unroll
        bf16x8 ah[4], al[4], bh[4], bl[4];
#pragma unroll
        for (int i = 0; i < 4; ++i) {
            ah[i] = *(const bf16x8*)&smem[b][0][wr * 4 + i][lane8];
            al[i] = *(const bf16x8*)&smem[b][1][wr * 4 + i][lane8];
            bh[i] = *(const bf16x8*)&smem[b][2][wc * 4 + i][lane8];
            bl[i] = *(const bf16x8*)&smem[b][3][wc * 4 + i][lane8];
        }
#pragma unroll
        for (int i = 0; i < 4; ++i)
#pragma unroll
            for (int j = 0; j < 4; ++j) {
                acc[i][j] = __builtin_amdgcn_mfma_f32_16x16x32_bf16(ah[i], bh[j], acc[i][j], 0, 0, 0);
                acc[i][j] = __builtin_amdgcn_mfma_f32_16x16x32_bf16(ah[i], bl[j], acc[i][j], 0, 0, 0);
                acc[i][j] = __builtin_amdgcn_mfma_f32_16x16x32_bf16(al[i], bh[j], acc[i][j], 0, 0, 0);
            }

        __builtin_amdgcn_sched_barrier(0);
        asm volatile("" ::: "memory");
        __builtin_amdgcn_s_barrier();          // all waves done reading buf b
        asm volatile("" ::: "memory");
        __builtin_amdgcn_sched_barrier(0);
        if (ks < 6) STAGE(b, (u32)(ks + 2) << 9);   // refill freed buffer
    }
#undef STAGE

    // epilogue: D row = (lane>>4)*4 + r, col = lane&15 (verified layout)
    const int slot = (blockIdx.y << 1) + wc;

#pragma unroll
    for (int i = 0; i < 4; ++i) {
#pragma unroll
        for (int r = 0; r < 4; ++r) {
            const int row = rb + wr * 64 + i * 16 + g * 4 + r;
            const float s0 = acc[i][0][r], s1 = acc[i][1][r];
            const float s2s = acc[i][2][r], s3 = acc[i][3][r];
            const float mm = fmaxf(fmaxf(s0, s1), fmaxf(s2s, s3));
            const u32 cj = (mm == s0) ? (u32)codes[0]
                         : (mm == s1) ? (u32)codes[1]
                         : (mm == s2s) ? (u32)codes[2] : (u32)codes[3];
            u64 key = ((u64)ford(-mm) << 32) | cj;
#pragma unroll
            for (int m = 1; m <= 8; m <<= 1) {       // reduce across 16-lane group
                const u64 o = shfl_xor_u64(key, m);
                key = (o < key) ? o : key;
            }
            if (li == 0) partial[((size_t)row << 8) + slot] = key;
        }
    }
}

// ---------------------------------------------------------------------------
// top-2 of 256 partial keys per row, exact fp32 re-check of both candidates,
// then write bneck / qidx / reg_z. One wave per row.
__global__ __launch_bounds__(256)
void finalize2(const u64* __restrict__ partial, const float* __restrict__ Z,
               const float* __restrict__ E, const float* __restrict__ z2,
               const float* __restrict__ e2,
               float* __restrict__ bneck, float* __restrict__ regz,
               int* __restrict__ qidx)
{
    const int t = threadIdx.x;
    const int row = (blockIdx.x << 2) + (t >> 6);
    const int lane = t & 63;
    const u64* p = partial + ((size_t)row << 8);

    u64 a1 = ~0ull, a2 = ~0ull;
#pragma unroll
    for (int q = 0; q < 4; ++q) {
        const u64 k = p[(q << 6) + lane];
        if (k < a1) { a2 = a1; a1 = k; }
        else if (k < a2) { a2 = k; }
    }
#pragma unroll
    for (int m = 1; m <= 32; m <<= 1) {   // butterfly top-2 merge
        const u64 b1 = shfl_xor_u64(a1, m);
        const u64 b2 = shfl_xor_u64(a2, m);
        if (b1 < a1) { a2 = (a1 < b2) ? a1 : b2; a1 = b1; }
        else         { a2 = (a2 < b1) ? a2 : b1; }
    }
    const u32 i1 = (u32)a1 & (KCODES - 1);
    const u32 i2 = (u32)a2 & (KCODES - 1);

    // exact fp32 distances for both candidates (mirrors np order of ops)
    const float4 zv  = *(const float4*)(Z + ((size_t)row << 8) + (lane << 2));
    const float4 c1v = *(const float4*)(E + ((size_t)i1 << 8) + (lane << 2));
    const float4 c2v = *(const float4*)(E + ((size_t)i2 << 8) + (lane << 2));
    float s1 = zv.x * c1v.x + zv.y * c1v.y + zv.z * c1v.z + zv.w * c1v.w;
    float s2 = zv.x * c2v.x + zv.y * c2v.y + zv.z * c2v.z + zv.w * c2v.w;
#pragma unroll
    for (int m = 32; m >= 1; m >>= 1) {
        s1 += __shfl_xor(s1, m, 64);
        s2 += __shfl_xor(s2, m, 64);
    }
    const float zz = z2[row];
    const float d1 = (zz + e2[i1]) - 2.0f * s1;
    const float d2 = (zz + e2[i2]) - 2.0f * s2;
    u32 win = i1;
    if (d2 < d1 || (d2 == d1 && i2 < i1)) win = i2;

    if (lane == 0) { qidx[row] = (int)win; bneck[row] = (float)win; }
    const float4 vw = *(const float4*)(E + ((size_t)win << 8) + (lane << 2));
    *(float4*)(regz + ((size_t)row << 8) + (lane << 2)) = vw;
}

// ---------------------------------------------------------------------------
// emb_out = emb @ W_out + b_out via bf16x3 MFMA. M=16384, N=1024, K=256.
// Round-3 single-buffer structure (kernel is only ~3% of runtime).
__global__ __launch_bounds__(256)
void embout_mfma(const u16* __restrict__ ah_p, const u16* __restrict__ al_p,
                 const u16* __restrict__ bh_p, const u16* __restrict__ bl_p,
                 const float* __restrict__ bias, float* __restrict__ C)
{
    __shared__ u16 smem[4][8][512];
    const int t = threadIdx.x;
    const int w = t >> 6, lane = t & 63;
    const int wr = w >> 1, wc = w & 1;
    const int rb = blockIdx.x << 7, cb = blockIdx.y << 7;
    const u32 lane8 = (u32)lane << 3;
    const int g = lane >> 4, li = lane & 15;

    const u32 ac0 = (u32)((rb >> 4) + w)     * 4096 + lane8;
    const u32 ac1 = (u32)((rb >> 4) + 4 + w) * 4096 + lane8;
    const u32 bc0 = (u32)((cb >> 4) + w)     * 4096 + lane8;
    const u32 bc1 = (u32)((cb >> 4) + 4 + w) * 4096 + lane8;

    u16* AhL0 = &smem[0][w][0];      u16* AhL1 = &smem[0][4 + w][0];
    u16* AlL0 = &smem[1][w][0];      u16* AlL1 = &smem[1][4 + w][0];
    u16* BhL0 = &smem[2][w][0];      u16* BhL1 = &smem[2][4 + w][0];
    u16* BlL0 = &smem[3][w][0];      u16* BlL1 = &smem[3][4 + w][0];

    f32x4 acc[4][4];
#pragma unroll
    for (int i = 0; i < 4; ++i)
#pragma unroll
        for (int j = 0; j < 4; ++j) acc[i][j] = (f32x4){0.f, 0.f, 0.f, 0.f};

    for (int ks = 0; ks < 8; ++ks) {
        const u32 ko = (u32)ks << 9;
        if (ks) __syncthreads();
        GLOAD16(ah_p + ac0 + ko, AhL0);  GLOAD16(ah_p + ac1 + ko, AhL1);
        GLOAD16(al_p + ac0 + ko, AlL0);  GLOAD16(al_p + ac1 + ko, AlL1);
        GLOAD16(bh_p + bc0 + ko, BhL0);  GLOAD16(bh_p + bc1 + ko, BhL1);
        GLOAD16(bl_p + bc0 + ko, BlL0);  GLOAD16(bl_p + bc1 + ko, BlL1);
        __syncthreads();

        bf16x8 ah[4], al[4], bh[4], bl[4];
#pragma unroll
        for (int i = 0; i < 4; ++i) {
            ah[i] = *(const bf16x8*)&smem[0][wr * 4 + i][lane8];
            al[i] = *(const bf16x8*)&smem[1][wr * 4 + i][lane8];
            bh[i] = *(const bf16x8*)&smem[2][wc * 4 + i][lane8];
            bl[i] = *(const bf16x8*)&smem[3][wc * 4 + i][lane8];
        }
#pragma unroll
        for (int i = 0; i < 4; ++i)
#pragma unroll
            for (int j = 0; j < 4; ++j) {
                acc[i][j] = __builtin_amdgcn_mfma_f32_16x16x32_bf16(ah[i], bh[j], acc[i][j], 0, 0, 0);
                acc[i][j] = __builtin_amdgcn_mfma_f32_16x16x32_bf16(ah[i], bl[j], acc[i][j], 0, 0, 0);
                acc[i][j] = __builtin_amdgcn_mfma_f32_16x16x32_bf16(al[i], bh[j], acc[i][j], 0, 0, 0);
            }
    }

    float bv[4];
#pragma unroll
    for (int j = 0; j < 4; ++j) bv[j] = bias[cb + wc * 64 + j * 16 + li];

#pragma unroll
    for (int i = 0; i < 4; ++i)
#pragma unroll
        for (int j = 0; j < 4; ++j) {
            const int col = cb + wc * 64 + j * 16 + li;
#pragma unroll
            for (int r = 0; r < 4; ++r) {
                const int m = rb + wr * 64 + i * 16 + g * 4 + r;
                C[(size_t)m * DIN + col] = acc[i][j][r] + bv[j];
            }
        }
}

// x_hat[row] = emb_out[qidx[row]] — one block per row, float4 copy
__global__ __launch_bounds__(256)
void gather_rows(const int* __restrict__ qidx, const float* __restrict__ S,
                 float* __restrict__ D)
{
    const int row = blockIdx.x;
    const int q = qidx[row] & (KCODES - 1);
    const float4 v = *(const float4*)(S + ((size_t)q << 10) + (threadIdx.x << 2));
    *(float4*)(D + ((size_t)row << 10) + (threadIdx.x << 2)) = v;
}

// ---------------------------------------------------------------------------
// fallback: x_hat = emb[qidx[row]] @ W_out(f32) + b_out (unchanged, verified)
__global__ __launch_bounds__(256)
void xhat_gemm(const int* __restrict__ qidx, const float* __restrict__ E,
               const float* __restrict__ B, const float* __restrict__ bias,
               float* __restrict__ C)
{
    __shared__ float As[16][132];
    __shared__ float Bs[16][132];
    const int t = threadIdx.x;
    const int w = t >> 6, lane = t & 63;
    const int tx = (lane & 7) | ((w & 1) << 3);
    const int ty = ((lane >> 3) & 7) | ((w >> 1) << 3);
    const int rb = blockIdx.x << 7;
    const int cb = blockIdx.y << 7;

    const int sr  = t >> 1;
    const int sk8 = (t & 1) << 3;
    const int bkr = t >> 4;
    const int bc8 = (t & 15) << 3;

    const int aidx = qidx[rb + sr] & (KCODES - 1);
    const float* Ap = E + (size_t)aidx * DB + sk8;
    const float* Bp = B + (size_t)bkr * DIN + cb + bc8;

    float acc[8][8];
#pragma unroll
    for (int i = 0; i < 8; ++i)
#pragma unroll
        for (int j = 0; j < 8; ++j) acc[i][j] = 0.0f;

    float4 a0 = *(const float4*)Ap;
    float4 a1 = *(const float4*)(Ap + 4);
    float4 b0 = *(const float4*)Bp;
    float4 b1 = *(const float4*)(Bp + 4);

    for (int kb = 0; kb < DB; kb += 16) {
        __syncthreads();
        As[sk8 + 0][sr] = a0.x; As[sk8 + 1][sr] = a0.y;
        As[sk8 + 2][sr] = a0.z; As[sk8 + 3][sr] = a0.w;
        As[sk8 + 4][sr] = a1.x; As[sk8 + 5][sr] = a1.y;
        As[sk8 + 6][sr] = a1.z; As[sk8 + 7][sr] = a1.w;
        *(float4*)&Bs[bkr][bc8]     = b0;
        *(float4*)&Bs[bkr][bc8 + 4] = b1;
        __syncthreads();
        if (kb + 16 < DB) {
            a0 = *(const float4*)(Ap + kb + 16);
            a1 = *(const float4*)(Ap + kb + 20);
            b0 = *(const float4*)(Bp + (size_t)(kb + 16) * DIN);
            b1 = *(const float4*)(Bp + (size_t)(kb + 16) * DIN + 4);
        }
#pragma unroll
        for (int kk = 0; kk < 16; ++kk) {
            float a[8], b[8];
            *(float4*)&a[0] = *(const float4*)&As[kk][ty * 8];
            *(float4*)&a[4] = *(const float4*)&As[kk][ty * 8 + 4];
            *(float4*)&b[0] = *(const float4*)&Bs[kk][tx * 8];
            *(float4*)&b[4] = *(const float4*)&Bs[kk][tx * 8 + 4];
#pragma unroll
            for (int i = 0; i < 8; ++i)
#pragma unroll
                for (int j = 0; j < 8; ++j)
                    acc[i][j] += a[i] * b[j];
        }
    }

    float bb[8];
#pragma unroll
    for (int j = 0; j < 8; ++j) bb[j] = bias[cb + tx * 8 + j];

#pragma unroll
    for (int i = 0; i < 8; ++i) {
        const size_t off = (size_t)(rb + ty * 8 + i) * DIN + cb + tx * 8;
        *(float4*)&C[off]     = make_float4(acc[i][0] + bb[0], acc[i][1] + bb[1],
                                            acc[i][2] + bb[2], acc[i][3] + bb[3]);
        *(float4*)&C[off + 4] = make_float4(acc[i][4] + bb[4], acc[i][5] + bb[5],
                                            acc[i][6] + bb[6], acc[i][7] + bb[7]);
    }
}

extern "C" void kernel_launch(void* const* d_in, const int* in_sizes, int n_in,
                              void* d_out, int out_size, void* d_ws, size_t ws_size,
                              hipStream_t stream)
{
    const float* x        = (const float*)d_in[0];
    const float* W_in     = (const float*)d_in[1];
    const float* b_in     = (const float*)d_in[2];
    const float* W_out    = (const float*)d_in[3];
    const float* b_out    = (const float*)d_in[4];
    const float* codebook = (const float*)d_in[5];
    const float* W_proj   = (const float*)d_in[6];
    const float* b_proj   = (const float*)d_in[7];

    // fp32 output layout, return order (x_hat, bneck, z, emb, reg_z)
    float* out   = (float*)d_out;
    float* xhat  = out;                   // 33,554,432 f  (written last)
    float* bneck = out + 33554432;        //     32,768 f
    float* z     = out + 33587200;        //  8,388,608 f
    float* emb   = out + 41975808;        //  4,194,304 f
    float* regz  = out + 46170112;        //  8,388,608 f  (written by finalize2)

    // scratch carved from not-yet-written output regions:
    //  - xhat region (134.2 MB): partial keys (64 MB) + eh/el packs (16.8 MB),
    //    all dead before xhat is written (by gather_rows or xhat_gemm).
    //  - regz region (33.55 MB): zh/zl packs, dead before finalize2 writes regz.
    char* outc = (char*)d_out;
    u64* partial = (u64*)outc;                        // 67,108,864 B
    u16* eh = (u16*)(outc + 67108864);                //  8,388,608 B
    u16* el = (u16*)(outc + 75497472);                //  8,388,608 B
    u16* zh = (u16*)(outc + 184680448);               // 16,777,216 B (regz start)
    u16* zl = (u16*)(outc + 201457664);               // 16,777,216 B

    // d_ws: small buffers + (if capacity) emb_out fast path
    char* ws = (char*)d_ws;
    float* e2   = (float*)ws;                 //  64 KB
    float* z2   = (float*)(ws + 65536);       // 128 KB
    int*   qidx = (int*)  (ws + 196608);      // 128 KB
    u16*   whh     = (u16*)  (ws + 327680);   // 512 KB
    u16*   whl     = (u16*)  (ws + 851968);   // 512 KB
    float* emb_out = (float*)(ws + 1376256);  // 67,108,864 B
    const bool fast_xhat = (ws_size >= (size_t)1376256 + 67108864);

    // 1. emb = codebook @ W_proj + b_proj
    sgemm_f32<<<dim3(128, 2), 256, 0, stream>>>(codebook, DB, W_proj, DB, b_proj,
                                                emb, DB, DB);
    // 2. split emb -> eh/el packs + e2 norms (fused)
    split_pack<<<KCODES / 8, 256, 0, stream>>>(emb, eh, el, e2);
    if (fast_xhat) {
        // 3. W_out -> fragment-packed bf16 planes; emb_out = emb @ W_out + b_out
        pack_wout<<<DIN / 8, 256, 0, stream>>>(W_out, whh, whl);
        embout_mfma<<<dim3(KCODES / 128, DIN / 128), 256, 0, stream>>>(
            eh, el, whh, whl, b_out, emb_out);
    }
    // 4. z = x @ W_in + b_in
    sgemm_f32<<<dim3(256, 2), 256, 0, stream>>>(x, DIN, W_in, DB, b_in,
                                                z, DB, DIN);
    // 5. split z -> zh/zl packs + z2 norms (fused)
    split_pack<<<M_ROWS / 8, 256, 0, stream>>>(z, zh, zl, z2);
    // 6. bf16x3 MFMA score GEMM + per-slice argmax-s keys (no atomics, no init)
    score_mfma<<<dim3(M_ROWS / 128, KCODES / 128), 256, 0, stream>>>(
        zh, zl, eh, el, e2, partial);
    // 7. top-2 + exact fp32 recheck; write bneck / qidx / reg_z
    finalize2<<<M_ROWS / 4, 256, 0, stream>>>(partial, z, emb, z2, e2,
                                              bneck, regz, qidx);
    // 8. x_hat
    if (fast_xhat) {
        gather_rows<<<M_ROWS, 256, 0, stream>>>(qidx, emb_out, xhat);
    } else {
        xhat_gemm<<<dim3(256, 8), 256, 0, stream>>>(qidx, emb, W_out, b_out, xhat);
    }
}

// Round 6
// 1371.113 us; speedup vs baseline: 1.0712x; 1.0451x over previous
//
#include <hip/hip_runtime.h>

typedef unsigned int u32;
typedef unsigned long long u64;
typedef unsigned short u16;

#define M_ROWS 32768
#define DB 256
#define DIN 1024
#define KCODES 16384

typedef __attribute__((ext_vector_type(8))) short bf16x8;   // 8 bf16 = 4 VGPR (MFMA A/B frag)
typedef __attribute__((ext_vector_type(4))) float f32x4;    // MFMA C/D frag
typedef __attribute__((ext_vector_type(8))) unsigned short us8;

// async global->LDS, 16B per lane; LDS dst = wave-uniform base + lane*16
#define GLOAD16(gp, lp) __builtin_amdgcn_global_load_lds( \
    (const __attribute__((address_space(1))) unsigned int*)(gp), \
    (__attribute__((address_space(3))) unsigned int*)(lp), 16, 0, 0)

// order-preserving fp32 -> u32 (finite values)
__device__ __forceinline__ u32 ford(float f) {
    u32 u = __float_as_uint(f);
    return (u & 0x80000000u) ? ~u : (u | 0x80000000u);
}
__device__ __forceinline__ u64 shfl_xor_u64(u64 v, int m) {
    u32 lo = (u32)v, hi = (u32)(v >> 32);
    lo = (u32)__shfl_xor((int)lo, m, 64);
    hi = (u32)__shfl_xor((int)hi, m, 64);
    return ((u64)hi << 32) | lo;
}
__device__ __forceinline__ u16 f2bf_rne(float f) {
    const u32 u = __float_as_uint(f);
    return (u16)((u + 0x7FFFu + ((u >> 16) & 1u)) >> 16);
}

// ---------------------------------------------------------------------------
// C(f32)[M,N] = A(f32)[M,Kd] @ B(f32)[Kd,N] + bias(f32)[N]
// block tile 128x128, BK=16, thread tile 8x8, 256 threads. (unchanged, verified)
__global__ __launch_bounds__(256)
void sgemm_f32(const float* __restrict__ A, int lda,
               const float* __restrict__ B, int ldb,
               const float* __restrict__ bias,
               float* __restrict__ C, int ldc, int Kd)
{
    __shared__ float As[16][132];
    __shared__ float Bs[16][132];
    const int t = threadIdx.x;
    const int w = t >> 6, lane = t & 63;
    const int tx = (lane & 7) | ((w & 1) << 3);
    const int ty = ((lane >> 3) & 7) | ((w >> 1) << 3);
    const int rb = blockIdx.x << 7;
    const int cb = blockIdx.y << 7;

    const int sr  = t >> 1;
    const int sk8 = (t & 1) << 3;
    const int bkr = t >> 4;
    const int bc8 = (t & 15) << 3;

    const float* Ap = A + (size_t)(rb + sr) * lda + sk8;
    const float* Bp = B + (size_t)bkr * ldb + cb + bc8;

    float acc[8][8];
#pragma unroll
    for (int i = 0; i < 8; ++i)
#pragma unroll
        for (int j = 0; j < 8; ++j) acc[i][j] = 0.0f;

    float4 a0 = *(const float4*)Ap;
    float4 a1 = *(const float4*)(Ap + 4);
    float4 b0 = *(const float4*)Bp;
    float4 b1 = *(const float4*)(Bp + 4);

    for (int kb = 0; kb < Kd; kb += 16) {
        __syncthreads();
        As[sk8 + 0][sr] = a0.x; As[sk8 + 1][sr] = a0.y;
        As[sk8 + 2][sr] = a0.z; As[sk8 + 3][sr] = a0.w;
        As[sk8 + 4][sr] = a1.x; As[sk8 + 5][sr] = a1.y;
        As[sk8 + 6][sr] = a1.z; As[sk8 + 7][sr] = a1.w;
        *(float4*)&Bs[bkr][bc8]     = b0;
        *(float4*)&Bs[bkr][bc8 + 4] = b1;
        __syncthreads();
        if (kb + 16 < Kd) {
            a0 = *(const float4*)(Ap + kb + 16);
            a1 = *(const float4*)(Ap + kb + 20);
            b0 = *(const float4*)(Bp + (size_t)(kb + 16) * ldb);
            b1 = *(const float4*)(Bp + (size_t)(kb + 16) * ldb + 4);
        }
#pragma unroll
        for (int kk = 0; kk < 16; ++kk) {
            float a[8], b[8];
            *(float4*)&a[0] = *(const float4*)&As[kk][ty * 8];
            *(float4*)&a[4] = *(const float4*)&As[kk][ty * 8 + 4];
            *(float4*)&b[0] = *(const float4*)&Bs[kk][tx * 8];
            *(float4*)&b[4] = *(const float4*)&Bs[kk][tx * 8 + 4];
#pragma unroll
            for (int i = 0; i < 8; ++i)
#pragma unroll
                for (int j = 0; j < 8; ++j)
                    acc[i][j] += a[i] * b[j];
        }
    }

    float bb[8];
#pragma unroll
    for (int j = 0; j < 8; ++j) bb[j] = bias[cb + tx * 8 + j];

#pragma unroll
    for (int i = 0; i < 8; ++i) {
        const size_t off = (size_t)(rb + ty * 8 + i) * ldc + cb + tx * 8;
        *(float4*)&C[off]     = make_float4(acc[i][0] + bb[0], acc[i][1] + bb[1],
                                            acc[i][2] + bb[2], acc[i][3] + bb[3]);
        *(float4*)&C[off + 4] = make_float4(acc[i][4] + bb[4], acc[i][5] + bb[5],
                                            acc[i][6] + bb[6], acc[i][7] + bb[7]);
    }
}

// ---------------------------------------------------------------------------
// z-GEMM with FUSED hi/lo bf16 fragment-pack epilogue.
// z = x @ W_in + b_in  (M=32768, K=1024, N=256); zh/zl emitted from registers,
// bit-identical to split_pack(f2bf_rne of the same fp32 value).
__global__ __launch_bounds__(256)
void sgemm_z_pack(const float* __restrict__ A, const float* __restrict__ B,
                  const float* __restrict__ bias, float* __restrict__ C,
                  u16* __restrict__ zh, u16* __restrict__ zl)
{
    __shared__ float As[16][132];
    __shared__ float Bs[16][132];
    const int t = threadIdx.x;
    const int w = t >> 6, lane = t & 63;
    const int tx = (lane & 7) | ((w & 1) << 3);
    const int ty = ((lane >> 3) & 7) | ((w >> 1) << 3);
    const int rb = blockIdx.x << 7;
    const int cb = blockIdx.y << 7;

    const int sr  = t >> 1;
    const int sk8 = (t & 1) << 3;
    const int bkr = t >> 4;
    const int bc8 = (t & 15) << 3;

    const float* Ap = A + (size_t)(rb + sr) * DIN + sk8;
    const float* Bp = B + (size_t)bkr * DB + cb + bc8;

    float acc[8][8];
#pragma unroll
    for (int i = 0; i < 8; ++i)
#pragma unroll
        for (int j = 0; j < 8; ++j) acc[i][j] = 0.0f;

    float4 a0 = *(const float4*)Ap;
    float4 a1 = *(const float4*)(Ap + 4);
    float4 b0 = *(const float4*)Bp;
    float4 b1 = *(const float4*)(Bp + 4);

    for (int kb = 0; kb < DIN; kb += 16) {
        __syncthreads();
        As[sk8 + 0][sr] = a0.x; As[sk8 + 1][sr] = a0.y;
        As[sk8 + 2][sr] = a0.z; As[sk8 + 3][sr] = a0.w;
        As[sk8 + 4][sr] = a1.x; As[sk8 + 5][sr] = a1.y;
        As[sk8 + 6][sr] = a1.z; As[sk8 + 7][sr] = a1.w;
        *(float4*)&Bs[bkr][bc8]     = b0;
        *(float4*)&Bs[bkr][bc8 + 4] = b1;
        __syncthreads();
        if (kb + 16 < DIN) {
            a0 = *(const float4*)(Ap + kb + 16);
            a1 = *(const float4*)(Ap + kb + 20);
            b0 = *(const float4*)(Bp + (size_t)(kb + 16) * DB);
            b1 = *(const float4*)(Bp + (size_t)(kb + 16) * DB + 4);
        }
#pragma unroll
        for (int kk = 0; kk < 16; ++kk) {
            float a[8], b[8];
            *(float4*)&a[0] = *(const float4*)&As[kk][ty * 8];
            *(float4*)&a[4] = *(const float4*)&As[kk][ty * 8 + 4];
            *(float4*)&b[0] = *(const float4*)&Bs[kk][tx * 8];
            *(float4*)&b[4] = *(const float4*)&Bs[kk][tx * 8 + 4];
#pragma unroll
            for (int i = 0; i < 8; ++i)
#pragma unroll
                for (int j = 0; j < 8; ++j)
                    acc[i][j] += a[i] * b[j];
        }
    }

    float bb[8];
#pragma unroll
    for (int j = 0; j < 8; ++j) bb[j] = bias[cb + tx * 8 + j];

#pragma unroll
    for (int i = 0; i < 8; ++i) {
        const int rg = rb + ty * 8 + i;
        float zr[8];
#pragma unroll
        for (int j = 0; j < 8; ++j) zr[j] = acc[i][j] + bb[j];
        const size_t off = (size_t)rg * DB + cb + tx * 8;
        *(float4*)&C[off]     = make_float4(zr[0], zr[1], zr[2], zr[3]);
        *(float4*)&C[off + 4] = make_float4(zr[4], zr[5], zr[6], zr[7]);
        // fragment-pack: elem(row,k) -> ((row>>4)*8+(k>>5))*512+((k>>3)&3)*128+(row&15)*8+(k&7)
        us8 hv, lv;
#pragma unroll
        for (int j = 0; j < 8; ++j) {
            const u16 h = f2bf_rne(zr[j]);
            hv[j] = h;
            lv[j] = f2bf_rne(zr[j] - __uint_as_float((u32)h << 16));
        }
        const size_t poff = ((size_t)(rg >> 4) * 8 + (size_t)(cb >> 5) + (tx >> 2)) * 512
                          + (size_t)(tx & 3) * 128 + ((rg & 15) << 3);
        *(us8*)(zh + poff) = hv;
        *(us8*)(zl + poff) = lv;
    }
}

// per-row squared norm (rows of length 256): one wave per row, 4 rows/block
__global__ __launch_bounds__(256)
void rowsq_kernel(const float* __restrict__ X, float* __restrict__ s2)
{
    const int t = threadIdx.x;
    const int row = (blockIdx.x << 2) + (t >> 6);
    const int lane = t & 63;
    const float4 v = *(const float4*)(X + (size_t)row * DB + (lane << 2));
    float s = v.x * v.x + v.y * v.y + v.z * v.z + v.w * v.w;
#pragma unroll
    for (int m = 32; m >= 1; m >>= 1) s += __shfl_xor(s, m, 64);
    if (lane == 0) s2[row] = s;
}

// ---------------------------------------------------------------------------
// split fp32 rows [nrows][256] into hi/lo bf16 planes (FRAGMENT-PACKED) and
// simultaneously emit per-row squared norms. (used for emb)
__global__ __launch_bounds__(256)
void split_pack(const float* __restrict__ X, u16* __restrict__ hi,
                u16* __restrict__ lo, float* __restrict__ s2)
{
    const int tid = (blockIdx.x << 8) + threadIdx.x;
    const int row = tid >> 5;
    const int kb  = (tid & 31) << 3;
    const float4 v0 = *(const float4*)(X + ((size_t)row << 8) + kb);
    const float4 v1 = *(const float4*)(X + ((size_t)row << 8) + kb + 4);
    const float f[8] = {v0.x, v0.y, v0.z, v0.w, v1.x, v1.y, v1.z, v1.w};
    us8 hv, lv;
    float s = 0.0f;
#pragma unroll
    for (int e = 0; e < 8; ++e) {
        const u16 h = f2bf_rne(f[e]);
        const float hf = __uint_as_float((u32)h << 16);
        hv[e] = h;
        lv[e] = f2bf_rne(f[e] - hf);
        s += f[e] * f[e];
    }
    const size_t off = ((size_t)(row >> 4) * 8 + (kb >> 5)) * 512
                     + (size_t)((kb >> 3) & 3) * 128 + ((row & 15) << 3);
    *(us8*)(hi + off) = hv;
    *(us8*)(lo + off) = lv;
#pragma unroll
    for (int m = 1; m <= 16; m <<= 1) s += __shfl_xor(s, m, 64);
    if ((threadIdx.x & 31) == 0) s2[row] = s;
}

// ---------------------------------------------------------------------------
// pack W_out [K=256][N=1024] (row-major) into fragment-packed bf16 hi/lo planes
// indexed by (n, k)
__global__ __launch_bounds__(256)
void pack_wout(const float* __restrict__ W, u16* __restrict__ hi, u16* __restrict__ lo)
{
    const int tid = (blockIdx.x << 8) + threadIdx.x;
    const int n  = tid >> 5;
    const int kb = (tid & 31) << 3;
    us8 hv, lv;
#pragma unroll
    for (int e = 0; e < 8; ++e) {
        const float f = W[(size_t)(kb + e) * DIN + n];
        const u16 h = f2bf_rne(f);
        hv[e] = h;
        lv[e] = f2bf_rne(f - __uint_as_float((u32)h << 16));
    }
    const size_t off = ((size_t)(n >> 4) * 8 + (kb >> 5)) * 512
                     + (size_t)((kb >> 3) & 3) * 128 + ((n & 15) << 3);
    *(us8*)(hi + off) = hv;
    *(us8*)(lo + off) = lv;
}

// ---------------------------------------------------------------------------
// bf16x3 MFMA distance GEMM + per-(row, 128-col-block) argmin key.
// 128x128 tile, 4 waves (2x2). Round-3-verified single-buffer K-loop (the
// 32KB/occupancy sweet spot; dbuf variants measured slower, r4/r5).
// acc init = -e2/2 => acc ends as s = dot - e2/2; argmin d == argmax s.
// Epilogue: cross-wave (wc) LDS merge -> ONE key per row per block (128 slots).
__global__ __launch_bounds__(256)
void score_mfma(const u16* __restrict__ zh, const u16* __restrict__ zl,
                const u16* __restrict__ eh, const u16* __restrict__ el,
                const float* __restrict__ e2, u64* __restrict__ partial)
{
    __shared__ u16 smem[4][8][512];   // [plane Zh,Zl,Eh,El][frag][512 elems] = 32KB
    __shared__ u64 lkeys[2][2][64];   // [wc][wr][local row] = 2KB
    const int t = threadIdx.x;
    const int w = t >> 6, lane = t & 63;
    const int wr = w >> 1, wc = w & 1;
    const int rb = blockIdx.x << 7, cb = blockIdx.y << 7;
    const u32 lane8 = (u32)lane << 3;
    const int g = lane >> 4, li = lane & 15;

    // global element offsets of the two 1KB chunks this wave stages per plane
    const u32 zc0 = (u32)((rb >> 4) + w)     * 4096 + lane8;
    const u32 zc1 = (u32)((rb >> 4) + 4 + w) * 4096 + lane8;
    const u32 ec0 = (u32)((cb >> 4) + w)     * 4096 + lane8;
    const u32 ec1 = (u32)((cb >> 4) + 4 + w) * 4096 + lane8;

    u16* ZhL0 = &smem[0][w][0];      u16* ZhL1 = &smem[0][4 + w][0];
    u16* ZlL0 = &smem[1][w][0];      u16* ZlL1 = &smem[1][4 + w][0];
    u16* EhL0 = &smem[2][w][0];      u16* EhL1 = &smem[2][4 + w][0];
    u16* ElL0 = &smem[3][w][0];      u16* ElL1 = &smem[3][4 + w][0];

    int codes[4];
    float e2v[4];
#pragma unroll
    for (int j = 0; j < 4; ++j) {
        codes[j] = cb + wc * 64 + j * 16 + li;
        e2v[j] = e2[codes[j]];
    }

    f32x4 acc[4][4];
#pragma unroll
    for (int i = 0; i < 4; ++i)
#pragma unroll
        for (int j = 0; j < 4; ++j) {
            const float v = -0.5f * e2v[j];
            acc[i][j] = (f32x4){v, v, v, v};
        }

    for (int ks = 0; ks < 8; ++ks) {
        const u32 ko = (u32)ks << 9;            // ks * 512 elems
        if (ks) __syncthreads();                // prev compute done reading LDS
        GLOAD16(zh + zc0 + ko, ZhL0);  GLOAD16(zh + zc1 + ko, ZhL1);
        GLOAD16(zl + zc0 + ko, ZlL0);  GLOAD16(zl + zc1 + ko, ZlL1);
        GLOAD16(eh + ec0 + ko, EhL0);  GLOAD16(eh + ec1 + ko, EhL1);
        GLOAD16(el + ec0 + ko, ElL0);  GLOAD16(el + ec1 + ko, ElL1);
        __syncthreads();                        // vmcnt(0) drained by compiler

        bf16x8 ah[4], al[4], bh[4], bl[4];
#pragma unroll
        for (int i = 0; i < 4; ++i) {
            ah[i] = *(const bf16x8*)&smem[0][wr * 4 + i][lane8];
            al[i] = *(const bf16x8*)&smem[1][wr * 4 + i][lane8];
            bh[i] = *(const bf16x8*)&smem[2][wc * 4 + i][lane8];
            bl[i] = *(const bf16x8*)&smem[3][wc * 4 + i][lane8];
        }
#pragma unroll
        for (int i = 0; i < 4; ++i)
#pragma unroll
            for (int j = 0; j < 4; ++j) {
                acc[i][j] = __builtin_amdgcn_mfma_f32_16x16x32_bf16(ah[i], bh[j], acc[i][j], 0, 0, 0);
                acc[i][j] = __builtin_amdgcn_mfma_f32_16x16x32_bf16(ah[i], bl[j], acc[i][j], 0, 0, 0);
                acc[i][j] = __builtin_amdgcn_mfma_f32_16x16x32_bf16(al[i], bh[j], acc[i][j], 0, 0, 0);
            }
    }

    // epilogue: D row = (lane>>4)*4 + r, col = lane&15 (verified layout)
#pragma unroll
    for (int i = 0; i < 4; ++i) {
#pragma unroll
        for (int r = 0; r < 4; ++r) {
            const float s0 = acc[i][0][r], s1 = acc[i][1][r];
            const float s2s = acc[i][2][r], s3 = acc[i][3][r];
            const float mm = fmaxf(fmaxf(s0, s1), fmaxf(s2s, s3));
            const u32 cj = (mm == s0) ? (u32)codes[0]
                         : (mm == s1) ? (u32)codes[1]
                         : (mm == s2s) ? (u32)codes[2] : (u32)codes[3];
            u64 key = ((u64)ford(-mm) << 32) | cj;
#pragma unroll
            for (int m = 1; m <= 8; m <<= 1) {       // reduce across 16-lane group
                const u64 o = shfl_xor_u64(key, m);
                key = (o < key) ? o : key;
            }
            if (li == 0) lkeys[wc][wr][i * 16 + g * 4 + r] = key;
        }
    }
    __syncthreads();
    if (wc == 0) {   // merge the two col-halves -> one key per row per block
        const u64 m0 = lkeys[0][wr][lane];
        const u64 m1 = lkeys[1][wr][lane];
        const u64 mk = (m0 < m1) ? m0 : m1;
        partial[((size_t)(rb + wr * 64 + lane) << 7) + blockIdx.y] = mk;
    }
}

// ---------------------------------------------------------------------------
// top-2 of 128 partial keys per row, exact fp32 re-check of both candidates,
// then write bneck / qidx / reg_z. One wave per row.
__global__ __launch_bounds__(256)
void finalize2(const u64* __restrict__ partial, const float* __restrict__ Z,
               const float* __restrict__ E, const float* __restrict__ z2,
               const float* __restrict__ e2,
               float* __restrict__ bneck, float* __restrict__ regz,
               int* __restrict__ qidx)
{
    const int t = threadIdx.x;
    const int row = (blockIdx.x << 2) + (t >> 6);
    const int lane = t & 63;
    const u64* p = partial + ((size_t)row << 7);

    const u64 k0 = p[lane];
    const u64 k1 = p[64 + lane];
    u64 a1 = (k0 < k1) ? k0 : k1;
    u64 a2 = (k0 < k1) ? k1 : k0;
#pragma unroll
    for (int m = 1; m <= 32; m <<= 1) {   // butterfly top-2 merge (keys distinct)
        const u64 b1 = shfl_xor_u64(a1, m);
        const u64 b2 = shfl_xor_u64(a2, m);
        if (b1 < a1) { a2 = (a1 < b2) ? a1 : b2; a1 = b1; }
        else         { a2 = (a2 < b1) ? a2 : b1; }
    }
    const u32 i1 = (u32)a1 & (KCODES - 1);
    const u32 i2 = (u32)a2 & (KCODES - 1);

    // exact fp32 distances for both candidates (mirrors np order of ops)
    const float4 zv  = *(const float4*)(Z + ((size_t)row << 8) + (lane << 2));
    const float4 c1v = *(const float4*)(E + ((size_t)i1 << 8) + (lane << 2));
    const float4 c2v = *(const float4*)(E + ((size_t)i2 << 8) + (lane << 2));
    float s1 = zv.x * c1v.x + zv.y * c1v.y + zv.z * c1v.z + zv.w * c1v.w;
    float s2 = zv.x * c2v.x + zv.y * c2v.y + zv.z * c2v.z + zv.w * c2v.w;
#pragma unroll
    for (int m = 32; m >= 1; m >>= 1) {
        s1 += __shfl_xor(s1, m, 64);
        s2 += __shfl_xor(s2, m, 64);
    }
    const float zz = z2[row];
    const float d1 = (zz + e2[i1]) - 2.0f * s1;
    const float d2 = (zz + e2[i2]) - 2.0f * s2;
    u32 win = i1;
    if (d2 < d1 || (d2 == d1 && i2 < i1)) win = i2;

    if (lane == 0) { qidx[row] = (int)win; bneck[row] = (float)win; }
    const float4 vw = *(const float4*)(E + ((size_t)win << 8) + (lane << 2));
    *(float4*)(regz + ((size_t)row << 8) + (lane << 2)) = vw;
}

// ---------------------------------------------------------------------------
// emb_out = emb @ W_out + b_out via bf16x3 MFMA. M=16384, N=1024, K=256.
// (round-3 verified structure)
__global__ __launch_bounds__(256)
void embout_mfma(const u16* __restrict__ ah_p, const u16* __restrict__ al_p,
                 const u16* __restrict__ bh_p, const u16* __restrict__ bl_p,
                 const float* __restrict__ bias, float* __restrict__ C)
{
    __shared__ u16 smem[4][8][512];
    const int t = threadIdx.x;
    const int w = t >> 6, lane = t & 63;
    const int wr = w >> 1, wc = w & 1;
    const int rb = blockIdx.x << 7, cb = blockIdx.y << 7;
    const u32 lane8 = (u32)lane << 3;
    const int g = lane >> 4, li = lane & 15;

    const u32 ac0 = (u32)((rb >> 4) + w)     * 4096 + lane8;
    const u32 ac1 = (u32)((rb >> 4) + 4 + w) * 4096 + lane8;
    const u32 bc0 = (u32)((cb >> 4) + w)     * 4096 + lane8;
    const u32 bc1 = (u32)((cb >> 4) + 4 + w) * 4096 + lane8;

    u16* AhL0 = &smem[0][w][0];      u16* AhL1 = &smem[0][4 + w][0];
    u16* AlL0 = &smem[1][w][0];      u16* AlL1 = &smem[1][4 + w][0];
    u16* BhL0 = &smem[2][w][0];      u16* BhL1 = &smem[2][4 + w][0];
    u16* BlL0 = &smem[3][w][0];      u16* BlL1 = &smem[3][4 + w][0];

    f32x4 acc[4][4];
#pragma unroll
    for (int i = 0; i < 4; ++i)
#pragma unroll
        for (int j = 0; j < 4; ++j) acc[i][j] = (f32x4){0.f, 0.f, 0.f, 0.f};

    for (int ks = 0; ks < 8; ++ks) {
        const u32 ko = (u32)ks << 9;
        if (ks) __syncthreads();
        GLOAD16(ah_p + ac0 + ko, AhL0);  GLOAD16(ah_p + ac1 + ko, AhL1);
        GLOAD16(al_p + ac0 + ko, AlL0);  GLOAD16(al_p + ac1 + ko, AlL1);
        GLOAD16(bh_p + bc0 + ko, BhL0);  GLOAD16(bh_p + bc1 + ko, BhL1);
        GLOAD16(bl_p + bc0 + ko, BlL0);  GLOAD16(bl_p + bc1 + ko, BlL1);
        __syncthreads();

        bf16x8 ah[4], al[4], bh[4], bl[4];
#pragma unroll
        for (int i = 0; i < 4; ++i) {
            ah[i] = *(const bf16x8*)&smem[0][wr * 4 + i][lane8];
            al[i] = *(const bf16x8*)&smem[1][wr * 4 + i][lane8];
            bh[i] = *(const bf16x8*)&smem[2][wc * 4 + i][lane8];
            bl[i] = *(const bf16x8*)&smem[3][wc * 4 + i][lane8];
        }
#pragma unroll
        for (int i = 0; i < 4; ++i)
#pragma unroll
            for (int j = 0; j < 4; ++j) {
                acc[i][j] = __builtin_amdgcn_mfma_f32_16x16x32_bf16(ah[i], bh[j], acc[i][j], 0, 0, 0);
                acc[i][j] = __builtin_amdgcn_mfma_f32_16x16x32_bf16(ah[i], bl[j], acc[i][j], 0, 0, 0);
                acc[i][j] = __builtin_amdgcn_mfma_f32_16x16x32_bf16(al[i], bh[j], acc[i][j], 0, 0, 0);
            }
    }

    float bv[4];
#pragma unroll
    for (int j = 0; j < 4; ++j) bv[j] = bias[cb + wc * 64 + j * 16 + li];

#pragma unroll
    for (int i = 0; i < 4; ++i)
#pragma unroll
        for (int j = 0; j < 4; ++j) {
            const int col = cb + wc * 64 + j * 16 + li;
#pragma unroll
            for (int r = 0; r < 4; ++r) {
                const int m = rb + wr * 64 + i * 16 + g * 4 + r;
                C[(size_t)m * DIN + col] = acc[i][j][r] + bv[j];
            }
        }
}

// x_hat[row] = emb_out[qidx[row]] — one block per row, float4 copy
__global__ __launch_bounds__(256)
void gather_rows(const int* __restrict__ qidx, const float* __restrict__ S,
                 float* __restrict__ D)
{
    const int row = blockIdx.x;
    const int q = qidx[row] & (KCODES - 1);
    const float4 v = *(const float4*)(S + ((size_t)q << 10) + (threadIdx.x << 2));
    *(float4*)(D + ((size_t)row << 10) + (threadIdx.x << 2)) = v;
}

// ---------------------------------------------------------------------------
// fallback: x_hat = emb[qidx[row]] @ W_out(f32) + b_out (unchanged, verified)
__global__ __launch_bounds__(256)
void xhat_gemm(const int* __restrict__ qidx, const float* __restrict__ E,
               const float* __restrict__ B, const float* __restrict__ bias,
               float* __restrict__ C)
{
    __shared__ float As[16][132];
    __shared__ float Bs[16][132];
    const int t = threadIdx.x;
    const int w = t >> 6, lane = t & 63;
    const int tx = (lane & 7) | ((w & 1) << 3);
    const int ty = ((lane >> 3) & 7) | ((w >> 1) << 3);
    const int rb = blockIdx.x << 7;
    const int cb = blockIdx.y << 7;

    const int sr  = t >> 1;
    const int sk8 = (t & 1) << 3;
    const int bkr = t >> 4;
    const int bc8 = (t & 15) << 3;

    const int aidx = qidx[rb + sr] & (KCODES - 1);
    const float* Ap = E + (size_t)aidx * DB + sk8;
    const float* Bp = B + (size_t)bkr * DIN + cb + bc8;

    float acc[8][8];
#pragma unroll
    for (int i = 0; i < 8; ++i)
#pragma unroll
        for (int j = 0; j < 8; ++j) acc[i][j] = 0.0f;

    float4 a0 = *(const float4*)Ap;
    float4 a1 = *(const float4*)(Ap + 4);
    float4 b0 = *(const float4*)Bp;
    float4 b1 = *(const float4*)(Bp + 4);

    for (int kb = 0; kb < DB; kb += 16) {
        __syncthreads();
        As[sk8 + 0][sr] = a0.x; As[sk8 + 1][sr] = a0.y;
        As[sk8 + 2][sr] = a0.z; As[sk8 + 3][sr] = a0.w;
        As[sk8 + 4][sr] = a1.x; As[sk8 + 5][sr] = a1.y;
        As[sk8 + 6][sr] = a1.z; As[sk8 + 7][sr] = a1.w;
        *(float4*)&Bs[bkr][bc8]     = b0;
        *(float4*)&Bs[bkr][bc8 + 4] = b1;
        __syncthreads();
        if (kb + 16 < DB) {
            a0 = *(const float4*)(Ap + kb + 16);
            a1 = *(const float4*)(Ap + kb + 20);
            b0 = *(const float4*)(Bp + (size_t)(kb + 16) * DIN);
            b1 = *(const float4*)(Bp + (size_t)(kb + 16) * DIN + 4);
        }
#pragma unroll
        for (int kk = 0; kk < 16; ++kk) {
            float a[8], b[8];
            *(float4*)&a[0] = *(const float4*)&As[kk][ty * 8];
            *(float4*)&a[4] = *(const float4*)&As[kk][ty * 8 + 4];
            *(float4*)&b[0] = *(const float4*)&Bs[kk][tx * 8];
            *(float4*)&b[4] = *(const float4*)&Bs[kk][tx * 8 + 4];
#pragma unroll
            for (int i = 0; i < 8; ++i)
#pragma unroll
                for (int j = 0; j < 8; ++j)
                    acc[i][j] += a[i] * b[j];
        }
    }

    float bb[8];
#pragma unroll
    for (int j = 0; j < 8; ++j) bb[j] = bias[cb + tx * 8 + j];

#pragma unroll
    for (int i = 0; i < 8; ++i) {
        const size_t off = (size_t)(rb + ty * 8 + i) * DIN + cb + tx * 8;
        *(float4*)&C[off]     = make_float4(acc[i][0] + bb[0], acc[i][1] + bb[1],
                                            acc[i][2] + bb[2], acc[i][3] + bb[3]);
        *(float4*)&C[off + 4] = make_float4(acc[i][4] + bb[4], acc[i][5] + bb[5],
                                            acc[i][6] + bb[6], acc[i][7] + bb[7]);
    }
}

extern "C" void kernel_launch(void* const* d_in, const int* in_sizes, int n_in,
                              void* d_out, int out_size, void* d_ws, size_t ws_size,
                              hipStream_t stream)
{
    const float* x        = (const float*)d_in[0];
    const float* W_in     = (const float*)d_in[1];
    const float* b_in     = (const float*)d_in[2];
    const float* W_out    = (const float*)d_in[3];
    const float* b_out    = (const float*)d_in[4];
    const float* codebook = (const float*)d_in[5];
    const float* W_proj   = (const float*)d_in[6];
    const float* b_proj   = (const float*)d_in[7];

    // fp32 output layout, return order (x_hat, bneck, z, emb, reg_z)
    float* out   = (float*)d_out;
    float* xhat  = out;                   // 33,554,432 f  (written last)
    float* bneck = out + 33554432;        //     32,768 f
    float* z     = out + 33587200;        //  8,388,608 f
    float* emb   = out + 41975808;        //  4,194,304 f
    float* regz  = out + 46170112;        //  8,388,608 f  (written by finalize2)

    // scratch carved from not-yet-written output regions:
    //  - xhat region (134.2 MB): partial keys (32 MB) + eh/el packs (16.8 MB),
    //    all dead before xhat is written (by gather_rows or xhat_gemm).
    //  - regz region (33.55 MB): zh/zl packs, dead before finalize2 writes regz.
    char* outc = (char*)d_out;
    u64* partial = (u64*)outc;                        // 33,554,432 B (128 slots/row)
    u16* eh = (u16*)(outc + 67108864);                //  8,388,608 B
    u16* el = (u16*)(outc + 75497472);                //  8,388,608 B
    u16* zh = (u16*)(outc + 184680448);               // 16,777,216 B (regz start)
    u16* zl = (u16*)(outc + 201457664);               // 16,777,216 B

    // d_ws: small buffers + (if capacity) emb_out fast path
    char* ws = (char*)d_ws;
    float* e2   = (float*)ws;                 //  64 KB
    float* z2   = (float*)(ws + 65536);       // 128 KB
    int*   qidx = (int*)  (ws + 196608);      // 128 KB
    u16*   whh     = (u16*)  (ws + 327680);   // 512 KB
    u16*   whl     = (u16*)  (ws + 851968);   // 512 KB
    float* emb_out = (float*)(ws + 1376256);  // 67,108,864 B
    const bool fast_xhat = (ws_size >= (size_t)1376256 + 67108864);

    // 1. emb = codebook @ W_proj + b_proj
    sgemm_f32<<<dim3(128, 2), 256, 0, stream>>>(codebook, DB, W_proj, DB, b_proj,
                                                emb, DB, DB);
    // 2. split emb -> eh/el packs + e2 norms (fused)
    split_pack<<<KCODES / 8, 256, 0, stream>>>(emb, eh, el, e2);
    if (fast_xhat) {
        // 3. W_out -> fragment-packed bf16 planes; emb_out = emb @ W_out + b_out
        pack_wout<<<DIN / 8, 256, 0, stream>>>(W_out, whh, whl);
        embout_mfma<<<dim3(KCODES / 128, DIN / 128), 256, 0, stream>>>(
            eh, el, whh, whl, b_out, emb_out);
    }
    // 4. z = x @ W_in + b_in, with FUSED zh/zl fragment-pack epilogue
    sgemm_z_pack<<<dim3(256, 2), 256, 0, stream>>>(x, W_in, b_in, z, zh, zl);
    // 5. per-row squared norms of z (for finalize2 exact recheck)
    rowsq_kernel<<<M_ROWS / 4, 256, 0, stream>>>(z, z2);
    // 6. bf16x3 MFMA score GEMM + per-block argmax-s keys (no atomics, no init)
    score_mfma<<<dim3(M_ROWS / 128, KCODES / 128), 256, 0, stream>>>(
        zh, zl, eh, el, e2, partial);
    // 7. top-2 + exact fp32 recheck; write bneck / qidx / reg_z
    finalize2<<<M_ROWS / 4, 256, 0, stream>>>(partial, z, emb, z2, e2,
                                              bneck, regz, qidx);
    // 8. x_hat
    if (fast_xhat) {
        gather_rows<<<M_ROWS, 256, 0, stream>>>(qidx, emb_out, xhat);
    } else {
        xhat_gemm<<<dim3(256, 8), 256, 0, stream>>>(qidx, emb, W_out, b_out, xhat);
    }
}